// Round 1
// baseline (1221.773 us; speedup 1.0000x reference)
//
#include <hip/hip_runtime.h>
#include <hip/hip_bf16.h>

#define N_CLASSES 1000
#define D 128

__device__ __forceinline__ void atomAddF(float* p, float v) {
    // native global_atomic_add_f32 on gfx90a+ (no CAS loop)
    unsafeAtomicAdd(p, v);
}

// Pass 1: per-class sums + counts. One wave handles 2 rows per iter:
// lanes 0-31 -> row s, lanes 32-63 -> row s+1; each lane loads float4 (16B).
__global__ void k_sums(const float* __restrict__ emb, const int* __restrict__ tgt,
                       float* __restrict__ sums, float* __restrict__ counts, int N) {
    const int gid   = blockIdx.x * blockDim.x + threadIdx.x;
    const int lane  = gid & 63;
    const int half  = lane >> 5;      // 0 or 1: which of the wave's 2 rows
    const int sub   = lane & 31;      // 0..31: column group (4 floats each)
    const int wid   = gid >> 6;
    const int nw    = (gridDim.x * blockDim.x) >> 6;

    for (int s = wid * 2 + half; s < N; s += nw * 2) {
        const int c = tgt[s];
        const float4 v = *reinterpret_cast<const float4*>(emb + (size_t)s * D + sub * 4);
        float* dst = sums + c * D + sub * 4;
        atomAddF(dst + 0, v.x);
        atomAddF(dst + 1, v.y);
        atomAddF(dst + 2, v.z);
        atomAddF(dst + 3, v.w);
        if (sub == 0) atomAddF(&counts[c], 1.0f);
    }
}

// Pass 1b: means[c][d] = sums[c][d] / max(count[c], 1)
__global__ void k_means(const float* __restrict__ sums, const float* __restrict__ counts,
                        float* __restrict__ means) {
    const int i = blockIdx.x * blockDim.x + threadIdx.x;
    if (i < N_CLASSES * D) {
        const float cnt = fmaxf(counts[i >> 7], 1.0f);
        means[i] = sums[i] / cnt;
    }
}

// Pass 2: per-sample L2 norm of (row - mean[class]), accumulate per class.
__global__ void k_norms(const float* __restrict__ emb, const int* __restrict__ tgt,
                        const float* __restrict__ means, float* __restrict__ normsums,
                        int N) {
    const int gid   = blockIdx.x * blockDim.x + threadIdx.x;
    const int lane  = gid & 63;
    const int half  = lane >> 5;
    const int sub   = lane & 31;
    const int wid   = gid >> 6;
    const int nw    = (gridDim.x * blockDim.x) >> 6;

    for (int s = wid * 2 + half; s < N; s += nw * 2) {
        const int c = tgt[s];
        const float4 v = *reinterpret_cast<const float4*>(emb + (size_t)s * D + sub * 4);
        const float4 m = *reinterpret_cast<const float4*>(means + c * D + sub * 4);
        const float dx = v.x - m.x, dy = v.y - m.y, dz = v.z - m.z, dw = v.w - m.w;
        float p = dx * dx + dy * dy + dz * dz + dw * dw;
        // reduce across the 32 lanes of this half-wave (masks 1..16 stay in-half)
        p += __shfl_xor(p, 1);
        p += __shfl_xor(p, 2);
        p += __shfl_xor(p, 4);
        p += __shfl_xor(p, 8);
        p += __shfl_xor(p, 16);
        if (sub == 0) atomAddF(&normsums[c], sqrtf(p));
    }
}

// Pass 3: final scalar = sum_c (count>0 ? normsum/count : 0)
__global__ void k_final(const float* __restrict__ counts, const float* __restrict__ normsums,
                        float* __restrict__ out) {
    __shared__ float red[256];
    float acc = 0.f;
    for (int c = threadIdx.x; c < N_CLASSES; c += 256) {
        const float cnt = counts[c];
        if (cnt > 0.f) acc += normsums[c] / cnt;
    }
    red[threadIdx.x] = acc;
    __syncthreads();
    for (int s = 128; s > 0; s >>= 1) {
        if (threadIdx.x < s) red[threadIdx.x] += red[threadIdx.x + s];
        __syncthreads();
    }
    if (threadIdx.x == 0) out[0] = red[0];
}

extern "C" void kernel_launch(void* const* d_in, const int* in_sizes, int n_in,
                              void* d_out, int out_size, void* d_ws, size_t ws_size,
                              hipStream_t stream) {
    const float* emb = (const float*)d_in[0];
    const int*   tgt = (const int*)d_in[1];
    const int N = in_sizes[1];

    char* ws = (char*)d_ws;
    float* sums     = (float*)(ws);                          // 1000*128 f32 = 512000 B
    float* means    = (float*)(ws + 512000);                 // 1000*128 f32 = 512000 B
    float* counts   = (float*)(ws + 1024000);                // 1000 f32
    float* normsums = (float*)(ws + 1028000);                // 1000 f32
    const size_t zero_bytes = 1032000;

    hipMemsetAsync(d_ws, 0, zero_bytes, stream);

    const int threads = 256;
    const int blocks  = 2048;   // 8192 waves, grid-stride

    k_sums<<<blocks, threads, 0, stream>>>(emb, tgt, sums, counts, N);
    k_means<<<(N_CLASSES * D + threads - 1) / threads, threads, 0, stream>>>(sums, counts, means);
    k_norms<<<blocks, threads, 0, stream>>>(emb, tgt, means, normsums, N);
    k_final<<<1, threads, 0, stream>>>(counts, normsums, (float*)d_out);
}

// Round 2
// 579.503 us; speedup vs baseline: 2.1083x; 2.1083x over previous
//
#include <hip/hip_runtime.h>
#include <hip/hip_bf16.h>

#define C 1000
#define D 128
#define NSLICE 4
#define SLICE 32          // floats per slice (128 B)
#define LSTRIDE 33        // +1 padding: bank = (c + 4*cg + j) % 32, classes spread
#define BLK 1024
#define WPB 64            // blocks per slice
#define NBLK (NSLICE*WPB) // 256 blocks = 1/CU

__device__ __forceinline__ void atomAddF(float* p, float v) { unsafeAtomicAdd(p, v); }

// Pass 1: LDS-privatized per-class sums for one 32-float D-slice per block.
__global__ __launch_bounds__(BLK, 1)
void k_sums_lds(const float* __restrict__ emb, const int* __restrict__ tgt,
                float* __restrict__ partials, float* __restrict__ pcounts,
                float* __restrict__ sums, float* __restrict__ counts,
                int N, int use_partials) {
    __shared__ float lsum[C * LSTRIDE];   // 132000 B
    __shared__ float lcnt[C];             // 4000 B
    const int t   = threadIdx.x;
    const int bid = blockIdx.x;
    const int s   = bid & (NSLICE - 1);   // slice id
    const int wi  = bid >> 2;             // within-slice block index 0..63

    for (int i = t; i < C * LSTRIDE; i += BLK) lsum[i] = 0.f;
    if (s == 0) for (int i = t; i < C; i += BLK) lcnt[i] = 0.f;
    __syncthreads();

    const int rpi = BLK / 8;              // 128 rows per block-iteration
    const int cg  = t & 7;                // column group within slice (4 floats)
    const int rl  = t >> 3;               // row within iteration
    for (int base = wi * rpi; base < N; base += WPB * rpi) {
        const int row = base + rl;
        if (row < N) {
            const int c = tgt[row];
            const float4 v = *reinterpret_cast<const float4*>(
                emb + (size_t)row * D + s * SLICE + cg * 4);
            float* p = lsum + c * LSTRIDE + cg * 4;
            atomicAdd(p + 0, v.x);
            atomicAdd(p + 1, v.y);
            atomicAdd(p + 2, v.z);
            atomicAdd(p + 3, v.w);
            if (s == 0 && cg == 0) atomicAdd(&lcnt[c], 1.0f);
        }
    }
    __syncthreads();

    if (use_partials) {
        // No atomics: each block dumps its private sums; k_reduce_means folds them.
        float* dst = partials + (size_t)bid * (C * SLICE);
        for (int i = t; i < C * SLICE; i += BLK)
            dst[i] = lsum[(i >> 5) * LSTRIDE + (i & 31)];
        if (s == 0) {
            float* dc = pcounts + wi * C;
            for (int i = t; i < C; i += BLK) dc[i] = lcnt[i];
        }
    } else {
        // Fallback (small ws): 8.2M atomics instead of 67M.
        for (int i = t; i < C * SLICE; i += BLK)
            atomAddF(&sums[(i >> 5) * D + s * SLICE + (i & 31)],
                     lsum[(i >> 5) * LSTRIDE + (i & 31)]);
        if (s == 0)
            for (int i = t; i < C; i += BLK) atomAddF(&counts[i], lcnt[i]);
    }
}

// Pass 1b (partials path): fold 64 partials/slice -> means + counts directly.
__global__ void k_reduce_means(const float* __restrict__ partials,
                               const float* __restrict__ pcounts,
                               float* __restrict__ means, float* __restrict__ counts) {
    const int cell = blockIdx.x * blockDim.x + threadIdx.x;
    if (cell >= C * D) return;
    const int c = cell >> 7;        // / 128
    const int d = cell & 127;
    const int s = d >> 5, j = d & 31;
    float sum = 0.f;
    const float* p = partials + (size_t)s * (C * SLICE) + c * SLICE + j;
    for (int wi = 0; wi < WPB; ++wi)
        sum += p[(size_t)wi * NSLICE * (C * SLICE)];
    float cnt = 0.f;
    const float* pc = pcounts + c;
    for (int wi = 0; wi < WPB; ++wi) cnt += pc[wi * C];   // 256 KB, L2-resident
    means[cell] = sum / fmaxf(cnt, 1.f);
    if (d == 0) counts[c] = cnt;
}

// Pass 1b (fallback path): means from atomically-built sums/counts.
__global__ void k_means(const float* __restrict__ sums, const float* __restrict__ counts,
                        float* __restrict__ means) {
    const int i = blockIdx.x * blockDim.x + threadIdx.x;
    if (i < C * D) means[i] = sums[i] / fmaxf(counts[i >> 7], 1.0f);
}

// Pass 2: per-sample L2 distance to class mean, accumulate per class.
__global__ void k_norms(const float* __restrict__ emb, const int* __restrict__ tgt,
                        const float* __restrict__ means, float* __restrict__ normsums,
                        int N) {
    const int gid  = blockIdx.x * blockDim.x + threadIdx.x;
    const int lane = gid & 63;
    const int half = lane >> 5;
    const int sub  = lane & 31;
    const int wid  = gid >> 6;
    const int nw   = (gridDim.x * blockDim.x) >> 6;

    for (int s = wid * 2 + half; s < N; s += nw * 2) {
        const int c = tgt[s];
        const float4 v = *reinterpret_cast<const float4*>(emb + (size_t)s * D + sub * 4);
        const float4 m = *reinterpret_cast<const float4*>(means + c * D + sub * 4);
        const float dx = v.x - m.x, dy = v.y - m.y, dz = v.z - m.z, dw = v.w - m.w;
        float p = dx * dx + dy * dy + dz * dz + dw * dw;
        p += __shfl_xor(p, 1);
        p += __shfl_xor(p, 2);
        p += __shfl_xor(p, 4);
        p += __shfl_xor(p, 8);
        p += __shfl_xor(p, 16);
        if (sub == 0) atomAddF(&normsums[c], sqrtf(p));
    }
}

// Pass 3: final scalar.
__global__ void k_final(const float* __restrict__ counts, const float* __restrict__ normsums,
                        float* __restrict__ out) {
    __shared__ float red[256];
    float acc = 0.f;
    for (int c = threadIdx.x; c < C; c += 256) {
        const float cnt = counts[c];
        if (cnt > 0.f) acc += normsums[c] / cnt;
    }
    red[threadIdx.x] = acc;
    __syncthreads();
    for (int s = 128; s > 0; s >>= 1) {
        if (threadIdx.x < s) red[threadIdx.x] += red[threadIdx.x + s];
        __syncthreads();
    }
    if (threadIdx.x == 0) out[0] = red[0];
}

extern "C" void kernel_launch(void* const* d_in, const int* in_sizes, int n_in,
                              void* d_out, int out_size, void* d_ws, size_t ws_size,
                              hipStream_t stream) {
    const float* emb = (const float*)d_in[0];
    const int*   tgt = (const int*)d_in[1];
    const int N = in_sizes[1];

    char* ws = (char*)d_ws;
    float* sums     = (float*)(ws);             // 512000 B
    float* counts   = (float*)(ws + 512000);    //   4000 B
    float* normsums = (float*)(ws + 516000);    //   4000 B
    float* means    = (float*)(ws + 520000);    // 512000 B
    float* partials = (float*)(ws + 1048576);   // 256 * 128000 B = 32.768 MB
    float* pcounts  = (float*)(ws + 1048576 + (size_t)NBLK * C * SLICE * 4); // 256000 B
    const size_t need = 1048576 + (size_t)NBLK * C * SLICE * 4 + (size_t)WPB * C * 4;
    const int use_partials = (ws_size >= need) ? 1 : 0;

    // zero sums+counts+normsums (sums/counts only needed by fallback; cheap)
    hipMemsetAsync(d_ws, 0, 520000, stream);

    k_sums_lds<<<NBLK, BLK, 0, stream>>>(emb, tgt, partials, pcounts, sums, counts,
                                         N, use_partials);
    if (use_partials) {
        k_reduce_means<<<(C * D + 255) / 256, 256, 0, stream>>>(partials, pcounts,
                                                                means, counts);
    } else {
        k_means<<<(C * D + 255) / 256, 256, 0, stream>>>(sums, counts, means);
    }
    k_norms<<<2048, 256, 0, stream>>>(emb, tgt, means, normsums, N);
    k_final<<<1, 256, 0, stream>>>(counts, normsums, (float*)d_out);
}

// Round 3
// 578.901 us; speedup vs baseline: 2.1105x; 1.0010x over previous
//
#include <hip/hip_runtime.h>
#include <hip/hip_bf16.h>

#define C 1000
#define D 128
#define NSLICE 4
#define SLICE 32          // floats per slice (128 B)
#define LSTRIDE 33        // +1 padding: bank = (c + 4*cg + j) % 32, classes spread
#define BLK 1024
#define WPB 64            // blocks per slice
#define NBLK (NSLICE*WPB) // 256 blocks = 1/CU

__device__ __forceinline__ void atomAddF(float* p, float v) { unsafeAtomicAdd(p, v); }

// Pass 1: LDS-privatized per-class sums for one 32-float D-slice per block.
// LDS atomics via unsafeAtomicAdd -> native ds_add_f32 (plain atomicAdd on
// shared f32 compiles to a CAS loop: measured ~206 cyc/wave-op in round 2).
__global__ __launch_bounds__(BLK, 1)
void k_sums_lds(const float* __restrict__ emb, const int* __restrict__ tgt,
                float* __restrict__ partials, float* __restrict__ pcounts,
                float* __restrict__ sums, float* __restrict__ counts,
                int N, int use_partials) {
    __shared__ float lsum[C * LSTRIDE];   // 132000 B
    __shared__ float lcnt[C];             // 4000 B
    const int t   = threadIdx.x;
    const int bid = blockIdx.x;
    const int s   = bid & (NSLICE - 1);   // slice id
    const int wi  = bid >> 2;             // within-slice block index 0..63

    for (int i = t; i < C * LSTRIDE; i += BLK) lsum[i] = 0.f;
    if (s == 0) for (int i = t; i < C; i += BLK) lcnt[i] = 0.f;
    __syncthreads();

    const int rpi = BLK / 8;              // 128 rows per block-iteration
    const int cg  = t & 7;                // column group within slice (4 floats)
    const int rl  = t >> 3;               // row within iteration
    for (int base = wi * rpi; base < N; base += WPB * rpi) {
        const int row = base + rl;
        if (row < N) {
            const int c = tgt[row];
            const float4 v = *reinterpret_cast<const float4*>(
                emb + (size_t)row * D + s * SLICE + cg * 4);
            float* p = lsum + c * LSTRIDE + cg * 4;
            atomAddF(p + 0, v.x);
            atomAddF(p + 1, v.y);
            atomAddF(p + 2, v.z);
            atomAddF(p + 3, v.w);
            if (s == 0 && cg == 0) atomAddF(&lcnt[c], 1.0f);
        }
    }
    __syncthreads();

    if (use_partials) {
        // No global atomics: each block dumps private sums; k_reduce_means folds.
        float* dst = partials + (size_t)bid * (C * SLICE);
        for (int i = t; i < C * SLICE; i += BLK)
            dst[i] = lsum[(i >> 5) * LSTRIDE + (i & 31)];
        if (s == 0) {
            float* dc = pcounts + wi * C;
            for (int i = t; i < C; i += BLK) dc[i] = lcnt[i];
        }
    } else {
        // Fallback (small ws): 8.2M atomics instead of 67M.
        for (int i = t; i < C * SLICE; i += BLK)
            atomAddF(&sums[(i >> 5) * D + s * SLICE + (i & 31)],
                     lsum[(i >> 5) * LSTRIDE + (i & 31)]);
        if (s == 0)
            for (int i = t; i < C; i += BLK) atomAddF(&counts[i], lcnt[i]);
    }
}

// Pass 1b (partials path): fold 64 partials/slice -> means + counts directly.
__global__ void k_reduce_means(const float* __restrict__ partials,
                               const float* __restrict__ pcounts,
                               float* __restrict__ means, float* __restrict__ counts) {
    const int cell = blockIdx.x * blockDim.x + threadIdx.x;
    if (cell >= C * D) return;
    const int c = cell >> 7;        // / 128
    const int d = cell & 127;
    const int s = d >> 5, j = d & 31;
    float sum = 0.f;
    const float* p = partials + (size_t)s * (C * SLICE) + c * SLICE + j;
    for (int wi = 0; wi < WPB; ++wi)
        sum += p[(size_t)wi * NSLICE * (C * SLICE)];
    float cnt = 0.f;
    const float* pc = pcounts + c;
    for (int wi = 0; wi < WPB; ++wi) cnt += pc[wi * C];   // 256 KB, L2-resident
    means[cell] = sum / fmaxf(cnt, 1.f);
    if (d == 0) counts[c] = cnt;
}

// Pass 1b (fallback path): means from atomically-built sums/counts.
__global__ void k_means(const float* __restrict__ sums, const float* __restrict__ counts,
                        float* __restrict__ means) {
    const int i = blockIdx.x * blockDim.x + threadIdx.x;
    if (i < C * D) means[i] = sums[i] / fmaxf(counts[i >> 7], 1.0f);
}

// Pass 2: per-sample L2 distance to class mean, accumulate per class.
// 2 rows per half-wave per iter; the two 5-deep shfl chains interleave (ILP).
__global__ void k_norms(const float* __restrict__ emb, const int* __restrict__ tgt,
                        const float* __restrict__ means, float* __restrict__ normsums,
                        int N) {
    const int gid  = blockIdx.x * blockDim.x + threadIdx.x;
    const int lane = gid & 63;
    const int half = lane >> 5;
    const int sub  = lane & 31;
    const int wid  = gid >> 6;
    const int nw   = (gridDim.x * blockDim.x) >> 6;

    for (int base = wid * 4; base < N; base += nw * 4) {
        const int r0 = base + half * 2;     // this half-wave's two rows
        const int r1 = r0 + 1;
        if (r1 < N) {
            const int c0 = tgt[r0];
            const int c1 = tgt[r1];
            const float4 v0 = *reinterpret_cast<const float4*>(emb + (size_t)r0 * D + sub * 4);
            const float4 v1 = *reinterpret_cast<const float4*>(emb + (size_t)r1 * D + sub * 4);
            const float4 m0 = *reinterpret_cast<const float4*>(means + c0 * D + sub * 4);
            const float4 m1 = *reinterpret_cast<const float4*>(means + c1 * D + sub * 4);
            float dx, dy, dz, dw;
            dx = v0.x - m0.x; dy = v0.y - m0.y; dz = v0.z - m0.z; dw = v0.w - m0.w;
            float p0 = dx * dx + dy * dy + dz * dz + dw * dw;
            dx = v1.x - m1.x; dy = v1.y - m1.y; dz = v1.z - m1.z; dw = v1.w - m1.w;
            float p1 = dx * dx + dy * dy + dz * dz + dw * dw;
            p0 += __shfl_xor(p0, 1);  p1 += __shfl_xor(p1, 1);
            p0 += __shfl_xor(p0, 2);  p1 += __shfl_xor(p1, 2);
            p0 += __shfl_xor(p0, 4);  p1 += __shfl_xor(p1, 4);
            p0 += __shfl_xor(p0, 8);  p1 += __shfl_xor(p1, 8);
            p0 += __shfl_xor(p0, 16); p1 += __shfl_xor(p1, 16);
            if (sub == 0) {
                atomAddF(&normsums[c0], sqrtf(p0));
                atomAddF(&normsums[c1], sqrtf(p1));
            }
        } else if (r0 < N) {          // tail
            const int c0 = tgt[r0];
            const float4 v0 = *reinterpret_cast<const float4*>(emb + (size_t)r0 * D + sub * 4);
            const float4 m0 = *reinterpret_cast<const float4*>(means + c0 * D + sub * 4);
            const float dx = v0.x - m0.x, dy = v0.y - m0.y, dz = v0.z - m0.z, dw = v0.w - m0.w;
            float p0 = dx * dx + dy * dy + dz * dz + dw * dw;
            p0 += __shfl_xor(p0, 1);
            p0 += __shfl_xor(p0, 2);
            p0 += __shfl_xor(p0, 4);
            p0 += __shfl_xor(p0, 8);
            p0 += __shfl_xor(p0, 16);
            if (sub == 0) atomAddF(&normsums[c0], sqrtf(p0));
        }
    }
}

// Pass 3: final scalar.
__global__ void k_final(const float* __restrict__ counts, const float* __restrict__ normsums,
                        float* __restrict__ out) {
    __shared__ float red[256];
    float acc = 0.f;
    for (int c = threadIdx.x; c < C; c += 256) {
        const float cnt = counts[c];
        if (cnt > 0.f) acc += normsums[c] / cnt;
    }
    red[threadIdx.x] = acc;
    __syncthreads();
    for (int s = 128; s > 0; s >>= 1) {
        if (threadIdx.x < s) red[threadIdx.x] += red[threadIdx.x + s];
        __syncthreads();
    }
    if (threadIdx.x == 0) out[0] = red[0];
}

extern "C" void kernel_launch(void* const* d_in, const int* in_sizes, int n_in,
                              void* d_out, int out_size, void* d_ws, size_t ws_size,
                              hipStream_t stream) {
    const float* emb = (const float*)d_in[0];
    const int*   tgt = (const int*)d_in[1];
    const int N = in_sizes[1];

    char* ws = (char*)d_ws;
    float* sums     = (float*)(ws);             // 512000 B
    float* counts   = (float*)(ws + 512000);    //   4000 B
    float* normsums = (float*)(ws + 516000);    //   4000 B
    float* means    = (float*)(ws + 520000);    // 512000 B
    float* partials = (float*)(ws + 1048576);   // 256 * 128000 B = 32.768 MB
    float* pcounts  = (float*)(ws + 1048576 + (size_t)NBLK * C * SLICE * 4); // 256000 B
    const size_t need = 1048576 + (size_t)NBLK * C * SLICE * 4 + (size_t)WPB * C * 4;
    const int use_partials = (ws_size >= need) ? 1 : 0;

    hipMemsetAsync(d_ws, 0, 520000, stream);

    k_sums_lds<<<NBLK, BLK, 0, stream>>>(emb, tgt, partials, pcounts, sums, counts,
                                         N, use_partials);
    if (use_partials) {
        k_reduce_means<<<(C * D + 255) / 256, 256, 0, stream>>>(partials, pcounts,
                                                                means, counts);
    } else {
        k_means<<<(C * D + 255) / 256, 256, 0, stream>>>(sums, counts, means);
    }
    k_norms<<<2048, 256, 0, stream>>>(emb, tgt, means, normsums, N);
    k_final<<<1, 256, 0, stream>>>(counts, normsums, (float*)d_out);
}

// Round 4
// 193.447 us; speedup vs baseline: 6.3158x; 2.9926x over previous
//
#include <hip/hip_runtime.h>
#include <hip/hip_bf16.h>

#define C 1000
#define D 128
#define PAD 16            // one atomic target per 64B line
#define SPLITS 8          // waves per class in k_class_sums

__device__ __forceinline__ void atomAddF(float* p, float v) { unsafeAtomicAdd(p, v); }

// Phase 1: histogram of target classes (LDS int atomics, native ds_add_u32).
__global__ __launch_bounds__(1024)
void k_hist(const int* __restrict__ tgt, unsigned* __restrict__ counts, int N) {
    __shared__ unsigned lh[C];
    const int t = threadIdx.x;
    if (t < C) lh[t] = 0u;
    __syncthreads();
    for (int i = blockIdx.x * 1024 + t; i < N; i += gridDim.x * 1024)
        atomicAdd(&lh[tgt[i]], 1u);
    __syncthreads();
    if (t < C) atomicAdd(&counts[t * PAD], lh[t]);
}

// Phase 2: exclusive scan over 1000 counts -> offsets, cursors, float counts.
__global__ __launch_bounds__(1024)
void k_scan(const unsigned* __restrict__ counts, int* __restrict__ off,
            int* __restrict__ cursor, float* __restrict__ countsf) {
    __shared__ unsigned a[1024];
    const int t = threadIdx.x;
    const unsigned mine = (t < C) ? counts[t * PAD] : 0u;
    a[t] = mine;
    for (int o = 1; o < 1024; o <<= 1) {
        __syncthreads();
        const unsigned v = (t >= o) ? a[t - o] : 0u;
        __syncthreads();
        a[t] += v;
    }
    __syncthreads();
    if (t < C) {
        const unsigned excl = a[t] - mine;
        off[t] = (int)excl;
        cursor[t * PAD] = (int)excl;
        countsf[t] = (float)mine;
    }
}

// Phase 3: scatter row indices into class-grouped order[] via atomic cursors.
__global__ __launch_bounds__(256)
void k_scatter(const int* __restrict__ tgt, int* __restrict__ cursor,
               int* __restrict__ order, int N) {
    const int i = blockIdx.x * 256 + threadIdx.x;
    if (i >= N) return;
    const int c = tgt[i];
    const int pos = atomicAdd(&cursor[c * PAD], 1);
    order[pos] = i;
}

// Phase 4: per-class sums -> means. One block per class, SPLITS waves.
// Half-wave (32 lanes x float4) reads one full 512B row coalesced; register
// accumulation, LDS fold. No accumulation atomics at all.
__global__ __launch_bounds__(64 * SPLITS)
void k_class_sums(const float* __restrict__ emb, const int* __restrict__ order,
                  const int* __restrict__ off, const unsigned* __restrict__ counts,
                  const float* __restrict__ countsf, float* __restrict__ means) {
    __shared__ float part[SPLITS][D];
    const int c     = blockIdx.x;
    const int t     = threadIdx.x;
    const int w     = t >> 6;
    const int lane  = t & 63;
    const int half  = lane >> 5;
    const int sub   = lane & 31;
    const int start = off[c];
    const int cnt   = (int)counts[c * PAD];
    const int chunk = (cnt + SPLITS - 1) / SPLITS;
    const int ws    = start + w * chunk;
    const int we    = min(start + cnt, ws + chunk);

    float ax = 0.f, ay = 0.f, az = 0.f, aw = 0.f;
    for (int pos = ws + half; pos < we; pos += 2) {
        const int ridx = order[pos];                       // broadcast load
        const float4 v = *reinterpret_cast<const float4*>(
            emb + (size_t)ridx * D + sub * 4);
        ax += v.x; ay += v.y; az += v.z; aw += v.w;
    }
    ax += __shfl_xor(ax, 32);
    ay += __shfl_xor(ay, 32);
    az += __shfl_xor(az, 32);
    aw += __shfl_xor(aw, 32);
    if (half == 0) {
        part[w][sub * 4 + 0] = ax;
        part[w][sub * 4 + 1] = ay;
        part[w][sub * 4 + 2] = az;
        part[w][sub * 4 + 3] = aw;
    }
    __syncthreads();
    if (t < D) {
        float s = 0.f;
        #pragma unroll
        for (int k = 0; k < SPLITS; ++k) s += part[k][t];
        means[c * D + t] = s / fmaxf(countsf[c], 1.f);
    }
}

// Phase 5: per-row L2 distance to class mean. Thread-per-row, no shuffles.
__global__ __launch_bounds__(256)
void k_norms(const float* __restrict__ emb, const int* __restrict__ tgt,
             const float* __restrict__ means, float* __restrict__ normsums, int N) {
    const int i = blockIdx.x * 256 + threadIdx.x;
    if (i >= N) return;
    const int c = tgt[i];
    const float4* er = reinterpret_cast<const float4*>(emb + (size_t)i * D);
    const float4* mr = reinterpret_cast<const float4*>(means + (size_t)c * D);
    float ax = 0.f, ay = 0.f, az = 0.f, aw = 0.f;
    #pragma unroll 4
    for (int j = 0; j < D / 4; ++j) {
        const float4 v = er[j];
        const float4 m = mr[j];
        const float dx = v.x - m.x, dy = v.y - m.y, dz = v.z - m.z, dw = v.w - m.w;
        ax += dx * dx; ay += dy * dy; az += dz * dz; aw += dw * dw;
    }
    atomAddF(&normsums[c * PAD], sqrtf(ax + ay + az + aw));
}

// Phase 6: final scalar = sum_c (count>0 ? normsum/count : 0)
__global__ __launch_bounds__(256)
void k_final(const float* __restrict__ countsf, const float* __restrict__ normsums,
             float* __restrict__ out) {
    __shared__ float red[256];
    float acc = 0.f;
    for (int c = threadIdx.x; c < C; c += 256) {
        const float cnt = countsf[c];
        if (cnt > 0.f) acc += normsums[c * PAD] / cnt;
    }
    red[threadIdx.x] = acc;
    __syncthreads();
    for (int s = 128; s > 0; s >>= 1) {
        if (threadIdx.x < s) red[threadIdx.x] += red[threadIdx.x + s];
        __syncthreads();
    }
    if (threadIdx.x == 0) out[0] = red[0];
}

extern "C" void kernel_launch(void* const* d_in, const int* in_sizes, int n_in,
                              void* d_out, int out_size, void* d_ws, size_t ws_size,
                              hipStream_t stream) {
    const float* emb = (const float*)d_in[0];
    const int*   tgt = (const int*)d_in[1];
    const int N = in_sizes[1];

    char* ws = (char*)d_ws;
    unsigned* counts   = (unsigned*)(ws);              // C*PAD u32 = 64000 B (zeroed)
    float*    normsums = (float*)(ws + 65536);         // C*PAD f32 = 64000 B (zeroed)
    int*      off      = (int*)(ws + 131072);          // C ints
    int*      cursor   = (int*)(ws + 139264);          // C*PAD ints = 64000 B
    float*    countsf  = (float*)(ws + 204800);        // C f32
    float*    means    = (float*)(ws + 212992);        // C*D f32 = 512000 B
    int*      order    = (int*)(ws + 729088);          // N ints = 2 MB

    hipMemsetAsync(d_ws, 0, 131072, stream);           // counts + normsums

    k_hist<<<256, 1024, 0, stream>>>(tgt, counts, N);
    k_scan<<<1, 1024, 0, stream>>>(counts, off, cursor, countsf);
    k_scatter<<<(N + 255) / 256, 256, 0, stream>>>(tgt, cursor, order, N);
    k_class_sums<<<C, 64 * SPLITS, 0, stream>>>(emb, order, off, counts, countsf, means);
    k_norms<<<(N + 255) / 256, 256, 0, stream>>>(emb, tgt, means, normsums, N);
    k_final<<<1, 256, 0, stream>>>(countsf, normsums, (float*)d_out);
}

// Round 5
// 138.405 us; speedup vs baseline: 8.8275x; 1.3977x over previous
//
#include <hip/hip_runtime.h>
#include <hip/hip_bf16.h>

#define C 1000
#define D 128
#define PAD 16            // one atomic target per 64B line

// Phase 1: histogram of target classes (LDS u32 atomics -> native ds_add).
__global__ __launch_bounds__(1024)
void k_hist(const int* __restrict__ tgt, unsigned* __restrict__ counts, int N) {
    __shared__ unsigned lh[C];
    const int t = threadIdx.x;
    if (t < C) lh[t] = 0u;
    __syncthreads();
    for (int i = blockIdx.x * 1024 + t; i < N; i += gridDim.x * 1024)
        atomicAdd(&lh[tgt[i]], 1u);
    __syncthreads();
    if (t < C) atomicAdd(&counts[t * PAD], lh[t]);
}

// Phase 2: exclusive scan over 1000 counts -> offsets + scatter cursors.
__global__ __launch_bounds__(1024)
void k_scan(const unsigned* __restrict__ counts, int* __restrict__ off,
            int* __restrict__ cursor) {
    __shared__ unsigned a[1024];
    const int t = threadIdx.x;
    const unsigned mine = (t < C) ? counts[t * PAD] : 0u;
    a[t] = mine;
    for (int o = 1; o < 1024; o <<= 1) {
        __syncthreads();
        const unsigned v = (t >= o) ? a[t - o] : 0u;
        __syncthreads();
        a[t] += v;
    }
    __syncthreads();
    if (t < C) {
        const unsigned excl = a[t] - mine;
        off[t] = (int)excl;
        cursor[t * PAD] = (int)excl;
    }
}

// Phase 3: scatter row indices into class-grouped order[].
__global__ __launch_bounds__(256)
void k_scatter(const int* __restrict__ tgt, int* __restrict__ cursor,
               int* __restrict__ order, int N) {
    const int i = blockIdx.x * 256 + threadIdx.x;
    if (i >= N) return;
    const int c = tgt[i];
    const int pos = atomicAdd(&cursor[c * PAD], 1);
    order[pos] = i;
}

// Phase 4 (fused): one block per class.
//   A: sum class rows (register float4 acc, half-wave = one 512B row) -> LDS fold
//      -> mean kept in LDS only.
//   B: re-read the same rows (L2/LLC-hot), L2 distance vs in-register mean,
//      5-step shfl reduce, accumulate sqrt in registers -> percls[c].
// No global atomics, no means round-trip through HBM.
__global__ __launch_bounds__(512)
void k_fused(const float* __restrict__ emb, const int* __restrict__ order,
             const int* __restrict__ off, const unsigned* __restrict__ counts,
             float* __restrict__ percls) {
    __shared__ float part[8][D];
    __shared__ float mean_l[D];
    __shared__ float nacc[16];
    const int c    = blockIdx.x;
    const int t    = threadIdx.x;
    const int w    = t >> 6;          // wave 0..7
    const int lane = t & 63;
    const int half = lane >> 5;
    const int sub  = lane & 31;
    const int hw   = t >> 5;          // half-wave 0..15
    const int start = off[c];
    const int cnt   = (int)counts[c * PAD];

    // --- A: class sum ---
    const int chunk = (cnt + 7) >> 3;
    const int wsrt  = start + w * chunk;
    const int wend  = min(start + cnt, wsrt + chunk);
    float ax = 0.f, ay = 0.f, az = 0.f, aw = 0.f;
    for (int pos = wsrt + half; pos < wend; pos += 2) {
        const int ridx = order[pos];
        const float4 v = *reinterpret_cast<const float4*>(
            emb + (size_t)ridx * D + sub * 4);
        ax += v.x; ay += v.y; az += v.z; aw += v.w;
    }
    ax += __shfl_xor(ax, 32);
    ay += __shfl_xor(ay, 32);
    az += __shfl_xor(az, 32);
    aw += __shfl_xor(aw, 32);
    if (half == 0) {
        part[w][sub * 4 + 0] = ax;
        part[w][sub * 4 + 1] = ay;
        part[w][sub * 4 + 2] = az;
        part[w][sub * 4 + 3] = aw;
    }
    __syncthreads();
    if (t < D) {
        float s = 0.f;
        #pragma unroll
        for (int k = 0; k < 8; ++k) s += part[k][t];
        mean_l[t] = s / fmaxf((float)cnt, 1.f);
    }
    __syncthreads();

    // --- B: norms vs mean (mean hoisted to registers) ---
    const float4 m = *reinterpret_cast<const float4*>(mean_l + sub * 4);
    float local = 0.f;
    for (int pos = start + hw; pos < start + cnt; pos += 16) {
        const int ridx = order[pos];
        const float4 v = *reinterpret_cast<const float4*>(
            emb + (size_t)ridx * D + sub * 4);
        const float dx = v.x - m.x, dy = v.y - m.y, dz = v.z - m.z, dw = v.w - m.w;
        float p = dx * dx + dy * dy + dz * dz + dw * dw;
        p += __shfl_xor(p, 1);
        p += __shfl_xor(p, 2);
        p += __shfl_xor(p, 4);
        p += __shfl_xor(p, 8);
        p += __shfl_xor(p, 16);
        if (sub == 0) local += sqrtf(p);
    }
    if (sub == 0) nacc[hw] = local;
    __syncthreads();
    if (t == 0) {
        float tot = 0.f;
        #pragma unroll
        for (int k = 0; k < 16; ++k) tot += nacc[k];
        percls[c] = (cnt > 0) ? tot / (float)cnt : 0.f;
    }
}

// Phase 5: final scalar = sum of per-class means of norms.
__global__ __launch_bounds__(256)
void k_final(const float* __restrict__ percls, float* __restrict__ out) {
    __shared__ float red[256];
    float acc = 0.f;
    for (int c = threadIdx.x; c < C; c += 256) acc += percls[c];
    red[threadIdx.x] = acc;
    __syncthreads();
    for (int s = 128; s > 0; s >>= 1) {
        if (threadIdx.x < s) red[threadIdx.x] += red[threadIdx.x + s];
        __syncthreads();
    }
    if (threadIdx.x == 0) out[0] = red[0];
}

extern "C" void kernel_launch(void* const* d_in, const int* in_sizes, int n_in,
                              void* d_out, int out_size, void* d_ws, size_t ws_size,
                              hipStream_t stream) {
    const float* emb = (const float*)d_in[0];
    const int*   tgt = (const int*)d_in[1];
    const int N = in_sizes[1];

    char* ws = (char*)d_ws;
    unsigned* counts = (unsigned*)(ws);            // C*PAD u32 = 64000 B (zeroed)
    int*      off    = (int*)(ws + 65536);         // C ints
    float*    percls = (float*)(ws + 73728);       // C f32
    int*      cursor = (int*)(ws + 131072);        // C*PAD ints
    int*      order  = (int*)(ws + 262144);        // N ints = 2 MB

    hipMemsetAsync(d_ws, 0, 65536, stream);        // counts only

    k_hist<<<256, 1024, 0, stream>>>(tgt, counts, N);
    k_scan<<<1, 1024, 0, stream>>>(counts, off, cursor);
    k_scatter<<<(N + 255) / 256, 256, 0, stream>>>(tgt, cursor, order, N);
    k_fused<<<C, 512, 0, stream>>>(emb, order, off, counts, percls);
    k_final<<<1, 256, 0, stream>>>(percls, (float*)d_out);
}

// Round 6
// 134.122 us; speedup vs baseline: 9.1094x; 1.0319x over previous
//
#include <hip/hip_runtime.h>
#include <hip/hip_bf16.h>

#define C 1000
#define D 128
#define PAD 16            // one atomic target per 64B line

__device__ __forceinline__ void atomAddF(float* p, float v) { unsafeAtomicAdd(p, v); }

// Phase 1: histogram of target classes (LDS u32 atomics -> native ds_add).
__global__ __launch_bounds__(1024)
void k_hist(const int* __restrict__ tgt, unsigned* __restrict__ counts, int N) {
    __shared__ unsigned lh[C];
    const int t = threadIdx.x;
    if (t < C) lh[t] = 0u;
    __syncthreads();
    for (int i = blockIdx.x * 1024 + t; i < N; i += gridDim.x * 1024)
        atomicAdd(&lh[tgt[i]], 1u);
    __syncthreads();
    if (t < C) atomicAdd(&counts[t * PAD], lh[t]);
}

// Phase 2: exclusive scan over 1000 counts -> offsets + scatter cursors.
__global__ __launch_bounds__(1024)
void k_scan(const unsigned* __restrict__ counts, int* __restrict__ off,
            int* __restrict__ cursor) {
    __shared__ unsigned a[1024];
    const int t = threadIdx.x;
    const unsigned mine = (t < C) ? counts[t * PAD] : 0u;
    a[t] = mine;
    for (int o = 1; o < 1024; o <<= 1) {
        __syncthreads();
        const unsigned v = (t >= o) ? a[t - o] : 0u;
        __syncthreads();
        a[t] += v;
    }
    __syncthreads();
    if (t < C) {
        const unsigned excl = a[t] - mine;
        off[t] = (int)excl;
        cursor[t * PAD] = (int)excl;
    }
}

// Phase 3: scatter row indices into class-grouped order[].
__global__ __launch_bounds__(256)
void k_scatter(const int* __restrict__ tgt, int* __restrict__ cursor,
               int* __restrict__ order, int N) {
    const int i = blockIdx.x * 256 + threadIdx.x;
    if (i >= N) return;
    const int c = tgt[i];
    const int pos = atomicAdd(&cursor[c * PAD], 1);
    order[pos] = i;
}

// Phase 4 (fused): one block per class; 2x-unrolled gathers for MLP.
__global__ __launch_bounds__(512)
void k_fused(const float* __restrict__ emb, const int* __restrict__ order,
             const int* __restrict__ off, const unsigned* __restrict__ counts,
             float* __restrict__ percls) {
    __shared__ float part[8][D];
    __shared__ float mean_l[D];
    __shared__ float nacc[16];
    const int c    = blockIdx.x;
    const int t    = threadIdx.x;
    const int w    = t >> 6;          // wave 0..7
    const int lane = t & 63;
    const int half = lane >> 5;
    const int sub  = lane & 31;
    const int hw   = t >> 5;          // half-wave 0..15
    const int start = off[c];
    const int cnt   = (int)counts[c * PAD];

    // --- A: class sum, 2 rows in flight per half-wave ---
    const int chunk = (cnt + 7) >> 3;
    const int wsrt  = start + w * chunk;
    const int wend  = min(start + cnt, wsrt + chunk);
    float ax = 0.f, ay = 0.f, az = 0.f, aw = 0.f;
    int pos = wsrt + half;
    for (; pos + 2 < wend; pos += 4) {
        const int r0 = order[pos];
        const int r1 = order[pos + 2];
        const float4 v0 = *reinterpret_cast<const float4*>(emb + (size_t)r0 * D + sub * 4);
        const float4 v1 = *reinterpret_cast<const float4*>(emb + (size_t)r1 * D + sub * 4);
        ax += v0.x; ay += v0.y; az += v0.z; aw += v0.w;
        ax += v1.x; ay += v1.y; az += v1.z; aw += v1.w;
    }
    for (; pos < wend; pos += 2) {
        const int r0 = order[pos];
        const float4 v0 = *reinterpret_cast<const float4*>(emb + (size_t)r0 * D + sub * 4);
        ax += v0.x; ay += v0.y; az += v0.z; aw += v0.w;
    }
    ax += __shfl_xor(ax, 32);
    ay += __shfl_xor(ay, 32);
    az += __shfl_xor(az, 32);
    aw += __shfl_xor(aw, 32);
    if (half == 0) {
        part[w][sub * 4 + 0] = ax;
        part[w][sub * 4 + 1] = ay;
        part[w][sub * 4 + 2] = az;
        part[w][sub * 4 + 3] = aw;
    }
    __syncthreads();
    if (t < D) {
        float s = 0.f;
        #pragma unroll
        for (int k = 0; k < 8; ++k) s += part[k][t];
        mean_l[t] = s / fmaxf((float)cnt, 1.f);
    }
    __syncthreads();

    // --- B: norms vs in-register mean, 2 rows + interleaved shfl chains ---
    const float4 m = *reinterpret_cast<const float4*>(mean_l + sub * 4);
    const int end = start + cnt;
    float local = 0.f;
    int q = start + hw;
    for (; q + 16 < end; q += 32) {
        const int r0 = order[q];
        const int r1 = order[q + 16];
        const float4 v0 = *reinterpret_cast<const float4*>(emb + (size_t)r0 * D + sub * 4);
        const float4 v1 = *reinterpret_cast<const float4*>(emb + (size_t)r1 * D + sub * 4);
        float dx, dy, dz, dw;
        dx = v0.x - m.x; dy = v0.y - m.y; dz = v0.z - m.z; dw = v0.w - m.w;
        float p0 = dx * dx + dy * dy + dz * dz + dw * dw;
        dx = v1.x - m.x; dy = v1.y - m.y; dz = v1.z - m.z; dw = v1.w - m.w;
        float p1 = dx * dx + dy * dy + dz * dz + dw * dw;
        p0 += __shfl_xor(p0, 1);  p1 += __shfl_xor(p1, 1);
        p0 += __shfl_xor(p0, 2);  p1 += __shfl_xor(p1, 2);
        p0 += __shfl_xor(p0, 4);  p1 += __shfl_xor(p1, 4);
        p0 += __shfl_xor(p0, 8);  p1 += __shfl_xor(p1, 8);
        p0 += __shfl_xor(p0, 16); p1 += __shfl_xor(p1, 16);
        if (sub == 0) local += sqrtf(p0) + sqrtf(p1);
    }
    for (; q < end; q += 16) {
        const int r0 = order[q];
        const float4 v0 = *reinterpret_cast<const float4*>(emb + (size_t)r0 * D + sub * 4);
        const float dx = v0.x - m.x, dy = v0.y - m.y, dz = v0.z - m.z, dw = v0.w - m.w;
        float p0 = dx * dx + dy * dy + dz * dz + dw * dw;
        p0 += __shfl_xor(p0, 1);
        p0 += __shfl_xor(p0, 2);
        p0 += __shfl_xor(p0, 4);
        p0 += __shfl_xor(p0, 8);
        p0 += __shfl_xor(p0, 16);
        if (sub == 0) local += sqrtf(p0);
    }
    if (sub == 0) nacc[hw] = local;
    __syncthreads();
    if (t == 0) {
        float tot = 0.f;
        #pragma unroll
        for (int k = 0; k < 16; ++k) tot += nacc[k];
        percls[c] = (cnt > 0) ? tot / (float)cnt : 0.f;
    }
}

// Phase 5: final scalar = sum of per-class means of norms.
__global__ __launch_bounds__(256)
void k_final(const float* __restrict__ percls, float* __restrict__ out) {
    __shared__ float red[256];
    float acc = 0.f;
    for (int c = threadIdx.x; c < C; c += 256) acc += percls[c];
    red[threadIdx.x] = acc;
    __syncthreads();
    for (int s = 128; s > 0; s >>= 1) {
        if (threadIdx.x < s) red[threadIdx.x] += red[threadIdx.x + s];
        __syncthreads();
    }
    if (threadIdx.x == 0) out[0] = red[0];
}

extern "C" void kernel_launch(void* const* d_in, const int* in_sizes, int n_in,
                              void* d_out, int out_size, void* d_ws, size_t ws_size,
                              hipStream_t stream) {
    const float* emb = (const float*)d_in[0];
    const int*   tgt = (const int*)d_in[1];
    const int N = in_sizes[1];

    char* ws = (char*)d_ws;
    unsigned* counts = (unsigned*)(ws);            // C*PAD u32 = 64000 B (zeroed)
    int*      off    = (int*)(ws + 65536);         // C ints
    float*    percls = (float*)(ws + 73728);       // C f32
    int*      cursor = (int*)(ws + 131072);        // C*PAD ints
    int*      order  = (int*)(ws + 262144);        // N ints = 2 MB

    hipMemsetAsync(d_ws, 0, 65536, stream);        // counts only

    k_hist<<<256, 1024, 0, stream>>>(tgt, counts, N);
    k_scan<<<1, 1024, 0, stream>>>(counts, off, cursor);
    k_scatter<<<(N + 255) / 256, 256, 0, stream>>>(tgt, cursor, order, N);
    k_fused<<<C, 512, 0, stream>>>(emb, order, off, counts, percls);
    k_final<<<1, 256, 0, stream>>>(percls, (float*)d_out);
}